// Round 3
// baseline (870.346 us; speedup 1.0000x reference)
//
#include <hip/hip_runtime.h>
#include <hip/hip_fp16.h>
#include <stdint.h>

typedef _Float16 half2v __attribute__((ext_vector_type(2)));
typedef _Float16 half4v __attribute__((ext_vector_type(4)));
typedef _Float16 half8v __attribute__((ext_vector_type(8)));
typedef float    float4v __attribute__((ext_vector_type(4)));

#define KDIM 2048
#define PDIM 512
#define MROWS 36864   // B*F*N = 32*32*36
#define NOBJ 36
#define NTOT 2048     // 4 * PDIM concatenated outputs
#define KT   32       // KDIM / 64

// ---------------- global -> LDS direct copy, 16B per lane ----------------
__device__ __forceinline__ void gload_lds16(const void* g, void* l) {
    using gptr_t = const __attribute__((address_space(1))) unsigned int*;
    using lptr_t = __attribute__((address_space(3))) unsigned int*;
    __builtin_amdgcn_global_load_lds((gptr_t)(uintptr_t)g,
                                     (lptr_t)(uint32_t)(uintptr_t)l,
                                     16, 0, 0);
}

// ------- kernel 0b: W [K][P] fp32 -> Wt [n][k] fp16 (4 mats concat on n) -------
__global__ __launch_bounds__(256)
void cvt_w_kernel(const float* __restrict__ Wp, const float* __restrict__ Ws,
                  const float* __restrict__ Wq, const float* __restrict__ Wr,
                  _Float16* __restrict__ wt) {
    const int bid = blockIdx.x;
    const int mat = bid >> 10;           // 1024 tiles per matrix (64 k-tiles x 16 p-tiles)
    const int t   = bid & 1023;
    const int kt  = t >> 4;              // 0..63
    const int pt  = t & 15;              // 0..15
    const float* W = (mat == 0) ? Wp : (mat == 1) ? Ws : (mat == 2) ? Wq : Wr;

    __shared__ float tile[32][33];
    const int tx = threadIdx.x & 31;
    const int ty = threadIdx.x >> 5;     // 0..7
    #pragma unroll
    for (int r = 0; r < 4; ++r) {
        const int k = kt * 32 + ty + r * 8;
        tile[ty + r * 8][tx] = W[(size_t)k * PDIM + pt * 32 + tx];
    }
    __syncthreads();
    #pragma unroll
    for (int r = 0; r < 4; ++r) {
        const int p = pt * 32 + ty + r * 8;
        const int n = mat * PDIM + p;
        wt[(size_t)n * KDIM + kt * 32 + tx] = (_Float16)tile[tx][ty + r * 8];
    }
}

// ---------------- kernel 1: fused cvt + 4-way projection GEMM ----------------
// 256x256 tile, BK=64. A read as f32 from x, reg-staged (T14: issue-early,
// cvt+ds_write-late); B via global_load_lds triple-buffer. ONE barrier + ONE
// counted vmcnt(4) gate per K-tile (no mid-tile WAR barrier: B(t+2) lands in
// the 3rd buffer). LDS = A 2x32K + B 3x32K = 160 KB exactly.
// Swizzle: LDS chunk c' = c ^ (row&7) on both write and read (conflict-free).
#define BARRIER() __builtin_amdgcn_s_barrier()

// B(kt_) half h_ -> buffer b_ (16 KB per half, 2 gloads x 512 threads x 16B)
#define STAGE_BH(b_, kt_, h_) do {                                            \
    const _Float16* g_ = pB + (size_t)(kt_) * 64 + (size_t)(h_) * 262144;     \
    char* l_ = (char*)sB + (b_) * 32768 + (h_) * 16384 + tid * 16;            \
    gload_lds16(g_, l_);                                                      \
    gload_lds16(g_ + 131072, l_ + 8192);                                      \
} while (0)

// A(kt_): 8x float4 (f32) into registers; thread covers rows arow+{0,64,128,192}
#define A_ISSUE(kt_) do {                                                     \
    const float* g_ = pX + (size_t)(kt_) * 64;                                \
    _Pragma("unroll")                                                         \
    for (int r_ = 0; r_ < 4; ++r_) {                                          \
        asr[2 * r_]     = *(const float4v*)(g_ + (size_t)r_ * 64 * KDIM);     \
        asr[2 * r_ + 1] = *(const float4v*)(g_ + (size_t)r_ * 64 * KDIM + 4); \
    }                                                                         \
} while (0)

// cvt the staged f32 -> f16 and write swizzled chunks into A buffer bdst_
#define A_WRITE(bdst_) do {                                                   \
    char* l_ = (char*)sA + (bdst_) * 32768 + dsAoff;                          \
    _Pragma("unroll")                                                         \
    for (int r_ = 0; r_ < 4; ++r_) {                                          \
        half8v h_;                                                            \
        h_[0] = (_Float16)asr[2*r_][0]; h_[1] = (_Float16)asr[2*r_][1];       \
        h_[2] = (_Float16)asr[2*r_][2]; h_[3] = (_Float16)asr[2*r_][3];       \
        h_[4] = (_Float16)asr[2*r_+1][0]; h_[5] = (_Float16)asr[2*r_+1][1];   \
        h_[6] = (_Float16)asr[2*r_+1][2]; h_[7] = (_Float16)asr[2*r_+1][3];   \
        *(half8v*)(l_ + r_ * 8192) = h_;                                      \
    }                                                                         \
} while (0)

#define LOAD_AF(b_, qm_) do {                                                 \
    const char* ba_ = (const char*)sA + (b_) * 32768 + wrbase;                \
    _Pragma("unroll")                                                         \
    for (int mi = 0; mi < 4; ++mi) {                                          \
        const int ro_ = ((qm_) * 64 + mi * 16 + r15) * 128;                   \
        af[mi][0] = *(const half8v*)(ba_ + ro_ + ck0);                        \
        af[mi][1] = *(const half8v*)(ba_ + ro_ + ck1);                        \
    }                                                                         \
} while (0)

#define LOAD_BF(b_, qn_, dst_) do {                                           \
    const char* bb_ = (const char*)sB + (b_) * 32768 + wcbase;                \
    _Pragma("unroll")                                                         \
    for (int ni = 0; ni < 2; ++ni) {                                          \
        const int ro_ = (rB0 + (qn_) * 32 + ni * 16 + r15) * 128;             \
        dst_[ni][0] = *(const half8v*)(bb_ + ro_ + ck0);                      \
        dst_[ni][1] = *(const half8v*)(bb_ + ro_ + ck1);                      \
    }                                                                         \
} while (0)

#define MFMA16(mb_, nb_, bf_) do {                                            \
    _Pragma("unroll")                                                         \
    for (int mi = 0; mi < 4; ++mi)                                            \
        _Pragma("unroll")                                                     \
        for (int ni = 0; ni < 2; ++ni) {                                      \
            acc[(mb_) + mi][(nb_) + ni] = __builtin_amdgcn_mfma_f32_16x16x32_f16( \
                af[mi][0], bf_[ni][0], acc[(mb_) + mi][(nb_) + ni], 0, 0, 0); \
            acc[(mb_) + mi][(nb_) + ni] = __builtin_amdgcn_mfma_f32_16x16x32_f16( \
                af[mi][1], bf_[ni][1], acc[(mb_) + mi][(nb_) + ni], 0, 0, 0); \
        }                                                                     \
} while (0)

// One K-tile, ONE barrier. VMEM FIFO at the gate:
// [B(t+1)x4 | A(t+1)f32 x8 | B(t+2)x4] -> vmcnt(4) waits B(t+1)+A(t+1),
// leaves B(t+2) in flight (never drain-0 in steady state).
#define ITER(t_, bA_, bB_, bB2_) do {                                         \
    if ((t_) + 1 < KT) A_ISSUE((t_) + 1);                                     \
    if ((t_) + 2 < KT) { STAGE_BH(bB2_, (t_) + 2, 0);                         \
                         STAGE_BH(bB2_, (t_) + 2, 1); }                       \
    __builtin_amdgcn_sched_barrier(0);  /* pin stage-issue before compute */  \
    LOAD_BF(bB_, 0, b0); LOAD_BF(bB_, 1, b1); LOAD_AF(bA_, 0);                \
    __builtin_amdgcn_s_setprio(1);                                            \
    MFMA16(0, 0, b0); MFMA16(0, 2, b1);                                       \
    __builtin_amdgcn_s_setprio(0);                                            \
    LOAD_AF(bA_, 1);                                                          \
    __builtin_amdgcn_s_setprio(1);                                            \
    MFMA16(4, 0, b0); MFMA16(4, 2, b1);                                       \
    __builtin_amdgcn_s_setprio(0);                                            \
    if ((t_) + 2 < KT) { asm volatile("s_waitcnt vmcnt(4)" ::: "memory"); }   \
    else               { asm volatile("s_waitcnt vmcnt(0)" ::: "memory"); }   \
    if ((t_) + 1 < KT) A_WRITE((bA_) ^ 1);                                    \
    asm volatile("s_waitcnt lgkmcnt(0)" ::: "memory");                        \
    BARRIER();                                                                \
    __builtin_amdgcn_sched_barrier(0);                                        \
} while (0)

__global__ __launch_bounds__(512, 1)
void proj_gemm(const float* __restrict__ X, const _Float16* __restrict__ Bt,
               float* __restrict__ rfeat, _Float16* __restrict__ sg,
               _Float16* __restrict__ ph, _Float16* __restrict__ vh,
               const float* __restrict__ bp, const float* __restrict__ bs,
               const float* __restrict__ bq) {
    __shared__ _Float16 sA[2 * 16384];    // 64 KiB (2 buf x 256 rows x 128 B)
    __shared__ _Float16 sB[3 * 16384];    // 96 KiB (3 buf)

    const int tid  = threadIdx.x;
    const int lane = tid & 63;
    const int wid  = tid >> 6;
    const int wr   = wid >> 2;            // 0..1  (M half owned by wave)
    const int wc   = wid & 3;             // 0..3  (N quarter owned by wave)
    const int r15  = lane & 15;
    const int k4   = lane >> 4;

    // bijective XCD swizzle (1152 % 8 == 0): each XCD gets 18 contiguous m-panels
    const int bid = blockIdx.x;
    const int swz = (bid & 7) * 144 + (bid >> 3);
    const int mt  = swz >> 3, nt = swz & 7;
    const int m0  = mt * 256, n0 = nt * 256;

    // A staging (f32, reg path): thread -> (row = arow + 64r, chunk c = lane&7)
    const int arow = wid * 8 + (lane >> 3);          // 0..63 ; row&7 == lane>>3
    const int ac   = lane & 7;
    const float* pX = X + (size_t)(m0 + arow) * KDIM + ac * 8;
    const int dsAoff = arow * 128 + ((ac ^ (lane >> 3)) << 4);

    // B staging source (swizzle baked into global address; LDS dest linear)
    const int srow = tid >> 3;                       // 0..63
    const int sk   = (tid & 7) ^ (srow & 7);
    const _Float16* pB = Bt + (size_t)(n0 + srow) * KDIM + sk * 8;

    // ds_read swizzled chunk offsets: row&7 == r15&7 for every fragment row
    const int ck0 = ((k4)     ^ (r15 & 7)) * 16;     // kk = 0
    const int ck1 = ((4 + k4) ^ (r15 & 7)) * 16;     // kk = 1
    const int wrbase = wr * 16384;
    const int wcbase = (wc >> 1) * 16384;
    const int rB0    = (wc & 1) * 64;

    half8v af[4][2], b0[2][2], b1[2][2];
    float4v asr[8];
    float4v acc[8][4] = {};

    // prologue: A(0) regs->cvt->bufA0 ; B(0)->buf0, B(1)->buf1 (stays in flight)
    A_ISSUE(0);
    STAGE_BH(0, 0, 0); STAGE_BH(0, 0, 1);
    STAGE_BH(1, 1, 0); STAGE_BH(1, 1, 1);
    A_WRITE(0);                                      // compiler waits f32 loads
    asm volatile("s_waitcnt vmcnt(4) lgkmcnt(0)" ::: "memory");  // B(0) + writes
    BARRIER();
    __builtin_amdgcn_sched_barrier(0);

    int bA = 0, bB = 0, bB2 = 2;
    #pragma unroll 2
    for (int t = 0; t < KT; ++t) {
        ITER(t, bA, bB, bB2);
        bA ^= 1;
        bB  = (bB  == 2) ? 0 : bB  + 1;
        bB2 = (bB2 == 2) ? 0 : bB2 + 1;
    }

    // epilogue: block-uniform output segment (n-span 256 never crosses 512)
    const int seg = n0 >> 9;                  // 0:proj 1:sigma 2:psi 3:r
    const int pn0 = (n0 & 511) + wc * 64;
    #pragma unroll
    for (int ni = 0; ni < 4; ++ni) {
        const int pcol = pn0 + ni * 16 + r15;
        float bias = 0.0f;
        if (seg == 0)      bias = bp[pcol];
        else if (seg == 1) bias = bs[pcol];
        else if (seg == 2) bias = bq[pcol];
        #pragma unroll
        for (int mi = 0; mi < 8; ++mi) {
            const int rb = m0 + wr * 128 + mi * 16 + k4 * 4;
            #pragma unroll
            for (int r = 0; r < 4; ++r) {
                const float val = acc[mi][ni][r] + bias;
                const size_t off = (size_t)(rb + r) * PDIM + pcol;
                if (seg == 0)      rfeat[off] = val;
                else if (seg == 1) sg[off] = (_Float16)val;
                else if (seg == 2) ph[off] = (_Float16)val;
                else               vh[off] = (_Float16)val;
            }
        }
    }
}

// ---------------- kernel 2: per-(b,f) attention, fp32 math ----------------
__global__ __launch_bounds__(256, 2)
void attn_kernel(const _Float16* __restrict__ sg, const _Float16* __restrict__ ph,
                 const _Float16* __restrict__ vh, float* __restrict__ rhat) {
    __shared__ _Float16 ss[NOBJ * 520];   // 512 + 8 pad halves per row
    __shared__ _Float16 ps[NOBJ * 520];
    __shared__ float    Ls[NOBJ * 37];

    const int tid = threadIdx.x;
    const size_t base = (size_t)blockIdx.x * (NOBJ * PDIM);

    for (int c = tid; c < (NOBJ * PDIM / 8); c += 256) {
        const int row = c >> 6;
        const int col = (c & 63) * 8;
        *(half8v*)&ss[row * 520 + col] = *(const half8v*)&sg[base + row * PDIM + col];
        *(half8v*)&ps[row * 520 + col] = *(const half8v*)&ph[base + row * PDIM + col];
    }
    __syncthreads();

    // logits: 12x12 grid of 3x3 register-blocked dot products (144 active threads)
    if (tid < 144) {
        const int i0 = (tid / 12) * 3;
        const int j0 = (tid % 12) * 3;
        float accv[3][3] = {};
        for (int p = 0; p < PDIM; p += 8) {
            half8v si[3], pj[3];
            #pragma unroll
            for (int ii = 0; ii < 3; ++ii) si[ii] = *(const half8v*)&ss[(i0 + ii) * 520 + p];
            #pragma unroll
            for (int jj = 0; jj < 3; ++jj) pj[jj] = *(const half8v*)&ps[(j0 + jj) * 520 + p];
            #pragma unroll
            for (int ii = 0; ii < 3; ++ii)
                #pragma unroll
                for (int jj = 0; jj < 3; ++jj) {
                    float t = accv[ii][jj];
                    #pragma unroll
                    for (int q = 0; q < 4; ++q) {
                        half2v x2; x2[0] = si[ii][2 * q]; x2[1] = si[ii][2 * q + 1];
                        half2v y2; y2[0] = pj[jj][2 * q]; y2[1] = pj[jj][2 * q + 1];
                        t = __builtin_amdgcn_fdot2(x2, y2, t, false);
                    }
                    accv[ii][jj] = t;
                }
        }
        #pragma unroll
        for (int ii = 0; ii < 3; ++ii)
            #pragma unroll
            for (int jj = 0; jj < 3; ++jj)
                Ls[(i0 + ii) * 37 + (j0 + jj)] = accv[ii][jj];
    }
    __syncthreads();

    // softmax per row (36 active threads), fp32
    if (tid < NOBJ) {
        float mx = -1e30f;
        for (int j = 0; j < NOBJ; ++j) mx = fmaxf(mx, Ls[tid * 37 + j]);
        float sum = 0.0f;
        for (int j = 0; j < NOBJ; ++j) {
            float e = __expf(Ls[tid * 37 + j] - mx);
            sum += e;
            Ls[tid * 37 + j] = e;
        }
        const float inv = 1.0f / sum;
        for (int j = 0; j < NOBJ; ++j) Ls[tid * 37 + j] *= inv;
    }
    __syncthreads();

    // AV: thread owns 4 cols (p4) x 18 rows (stride 2); v streamed from global
    const int p4 = (tid & 127) * 4;
    const int r0 = tid >> 7;
    float4v acc[18] = {};
    for (int j = 0; j < NOBJ; ++j) {
        half4v v4 = *(const half4v*)&vh[base + (size_t)j * PDIM + p4];
        float4v vf;
        vf[0] = (float)v4[0]; vf[1] = (float)v4[1];
        vf[2] = (float)v4[2]; vf[3] = (float)v4[3];
        #pragma unroll
        for (int m = 0; m < 18; ++m) {
            const float aw = Ls[(2 * m + r0) * 37 + j];
            acc[m] += aw * vf;
        }
    }
    #pragma unroll
    for (int m = 0; m < 18; ++m)
        *(float4v*)&rhat[base + (size_t)(2 * m + r0) * PDIM + p4] = acc[m];
}

extern "C" void kernel_launch(void* const* d_in, const int* in_sizes, int n_in,
                              void* d_out, int out_size, void* d_ws, size_t ws_size,
                              hipStream_t stream) {
    const float* x   = (const float*)d_in[0];
    const float* Wp  = (const float*)d_in[1];
    const float* bp  = (const float*)d_in[2];
    const float* Wsg = (const float*)d_in[3];
    const float* bsg = (const float*)d_in[4];
    const float* Wps = (const float*)d_in[5];
    const float* bps = (const float*)d_in[6];
    const float* Wr  = (const float*)d_in[7];
    float* out = (float*)d_out;

    // workspace layout (bytes): wt 8,388,608 | sig/psi/v 37,748,736 each
    char* ws = (char*)d_ws;
    _Float16* wt = (_Float16*)(ws);
    _Float16* sg = (_Float16*)(ws + 8388608UL);
    _Float16* ph = (_Float16*)(ws + 46137344UL);
    _Float16* vh = (_Float16*)(ws + 83886080UL);

    cvt_w_kernel<<<4096, 256, 0, stream>>>(Wp, Wsg, Wps, Wr, wt);
    // (M/256=144) x (NTOT/256=8) tiles, 512 threads, 160 KiB LDS (static)
    proj_gemm<<<144 * 8, 512, 0, stream>>>(x, wt, out, sg, ph, vh, bp, bsg, bps);
    attn_kernel<<<1024, 256, 0, stream>>>(sg, ph, vh, out + 18874368);
}